// Round 1
// baseline (95.140 us; speedup 1.0000x reference)
//
#include <hip/hip_runtime.h>

// Problem constants
#define B_TOT   65536
#define IN_DIM  512
#define H0      256
#define H1      128
#define HH      64
#define NDIS    12

typedef __bf16 bf16_t;
typedef __bf16 bf16x4 __attribute__((ext_vector_type(4)));
typedef __bf16 bf16x8 __attribute__((ext_vector_type(8)));
typedef float  f32x4  __attribute__((ext_vector_type(4)));
typedef float  floatx4 __attribute__((ext_vector_type(4)));

// ---- workspace layout (bytes) ----
#define WS_W0T   0u          // bf16 [256][512]  = 262144 B   (W0t[c][k] = W0[k][c])
#define WS_W1T   262144u     // bf16 [128][256]  = 65536 B    (W1t[c][k] = W1[k][c])
#define WS_WZT   327680u     // bf16 [12][64][128] = 196608 B (Wzt[d][h][e] = Wz[d][e][h])
#define WS_WIT   524288u     // bf16 [16][128]   = 4096 B     (w_init rows, zero-padded to 16)
#define WS_AL0   528384u     // f32 [256]
#define WS_BE0   529408u     // f32 [256]
#define WS_AL1   530432u     // f32 [128]
#define WS_BE1   530944u     // f32 [128]
#define WS_Z     531456u     // bf16 [65536][128] = 16777216 B
#define WS_NEED  (531456u + 16777216u)

// =====================================================================
// Prep: transpose + f32->bf16 weights, fold BN (+linear bias) into alpha/beta
// =====================================================================
__global__ void prep_kernel(const float* __restrict__ W0, const float* __restrict__ b0,
                            const float* __restrict__ g0, const float* __restrict__ bb0,
                            const float* __restrict__ mm0, const float* __restrict__ vv0,
                            const float* __restrict__ W1, const float* __restrict__ b1,
                            const float* __restrict__ g1, const float* __restrict__ bb1,
                            const float* __restrict__ mm1, const float* __restrict__ vv1,
                            const float* __restrict__ w_init, const float* __restrict__ Wz,
                            char* __restrict__ ws)
{
    bf16_t* W0t = (bf16_t*)(ws + WS_W0T);
    bf16_t* W1t = (bf16_t*)(ws + WS_W1T);
    bf16_t* Wzt = (bf16_t*)(ws + WS_WZT);
    bf16_t* wiT = (bf16_t*)(ws + WS_WIT);
    float* al0 = (float*)(ws + WS_AL0);
    float* be0 = (float*)(ws + WS_BE0);
    float* al1 = (float*)(ws + WS_AL1);
    float* be1 = (float*)(ws + WS_BE1);

    int t = blockIdx.x * 256 + threadIdx.x;   // grid = 512*256 = 131072 threads

    { // W0t: 256*512 = 131072 elems (exactly one per thread)
        int c = t >> 9, k = t & 511;
        W0t[t] = (bf16_t)W0[k * H0 + c];
    }
    if (t < H1 * H0) { // W1t: 128*256
        int c = t >> 8, k = t & 255;
        W1t[t] = (bf16_t)W1[k * H1 + c];
    }
    if (t < NDIS * HH * H1) { // Wzt: 12*64*128 ; Wz is [12][128][64]
        int d = t >> 13, r = t & 8191, h = r >> 7, e = r & 127;
        Wzt[t] = (bf16_t)Wz[d * 8192 + e * 64 + h];
    }
    if (t < 16 * H1) { // w_initT (pad D 12->16 with zeros); w_init is [12][128]
        int d = t >> 7, e = t & 127;
        wiT[t] = (d < NDIS) ? (bf16_t)w_init[d * H1 + e] : (bf16_t)0.0f;
    }
    if (t < H0) {
        float a = g0[t] * rsqrtf(vv0[t] + 1e-5f);
        al0[t] = a;
        be0[t] = (b0[t] - mm0[t]) * a + bb0[t];
    }
    if (t < H1) {
        float a = g1[t] * rsqrtf(vv1[t] + 1e-5f);
        al1[t] = a;
        be1[t] = (b1[t] - mm1[t]) * a + bb1[t];
    }
}

// =====================================================================
// Encoder: x[64 rows] -> h (LDS) -> z (ws, bf16), BN+ReLU fused.
// Block = 512 threads = 8 waves arranged 2x4 (wave tile GEMM0: 32x64, GEMM1: 32x32).
// =====================================================================
__global__ __launch_bounds__(512, 4) void enc_kernel(
    const float* __restrict__ x,
    const bf16_t* __restrict__ W0t, const bf16_t* __restrict__ W1t,
    const float* __restrict__ al0, const float* __restrict__ be0,
    const float* __restrict__ al1, const float* __restrict__ be1,
    bf16_t* __restrict__ z_ws)
{
    // Phase A: xs [64][72] (9216 B) + w0s [256][72] (36864 B) = 46080 B
    // Phase B: hs [64][264] (33792 B) aliases the same region.
    __shared__ __align__(16) char smem[46080];
    bf16_t* xs  = (bf16_t*)smem;
    bf16_t* w0s = (bf16_t*)(smem + 9216);
    bf16_t* hs  = (bf16_t*)smem;

    const int tid  = threadIdx.x;
    const int lane = tid & 63, wid = tid >> 6;
    const int wr = wid >> 2, wc = wid & 3;    // 2 row-groups x 4 col-groups
    const int l15 = lane & 15, lg = lane >> 4;
    const int m0 = blockIdx.x * 64;

    f32x4 acc[2][4] = {};
    for (int ks = 0; ks < 8; ++ks) {          // K = 512, BK = 64
        // stage x tile (f32 -> bf16)
        #pragma unroll
        for (int i = 0; i < 2; ++i) {
            int flat = i * 512 + tid;         // 0..1023
            int row = flat >> 4, c4 = (flat & 15) << 2;
            floatx4 v = *(const floatx4*)(x + (m0 + row) * IN_DIM + ks * 64 + c4);
            bf16x4 o;
            o[0] = (bf16_t)v[0]; o[1] = (bf16_t)v[1];
            o[2] = (bf16_t)v[2]; o[3] = (bf16_t)v[3];
            *(bf16x4*)(xs + row * 72 + c4) = o;
        }
        // stage W0t tile (bf16 copy, [c][k])
        #pragma unroll
        for (int i = 0; i < 4; ++i) {
            int flat = i * 512 + tid;         // 0..2047
            int c = flat >> 3, k8 = (flat & 7) << 3;
            *(bf16x8*)(w0s + c * 72 + k8) = *(const bf16x8*)(W0t + c * IN_DIM + ks * 64 + k8);
        }
        __syncthreads();
        #pragma unroll
        for (int kf = 0; kf < 2; ++kf) {
            bf16x8 a[2], b[4];
            #pragma unroll
            for (int mr = 0; mr < 2; ++mr)
                a[mr] = *(const bf16x8*)(xs + (wr * 32 + mr * 16 + l15) * 72 + kf * 32 + lg * 8);
            #pragma unroll
            for (int nr = 0; nr < 4; ++nr)
                b[nr] = *(const bf16x8*)(w0s + (wc * 64 + nr * 16 + l15) * 72 + kf * 32 + lg * 8);
            #pragma unroll
            for (int mr = 0; mr < 2; ++mr)
                #pragma unroll
                for (int nr = 0; nr < 4; ++nr)
                    acc[mr][nr] = __builtin_amdgcn_mfma_f32_16x16x32_bf16(a[mr], b[nr], acc[mr][nr], 0, 0, 0);
        }
        __syncthreads();
    }

    // epilogue A: BN0 + ReLU -> hs (bf16)  (D layout: col = l15, row = lg*4+j)
    #pragma unroll
    for (int mr = 0; mr < 2; ++mr)
        #pragma unroll
        for (int nr = 0; nr < 4; ++nr) {
            int c = wc * 64 + nr * 16 + l15;
            float alpha = al0[c], beta = be0[c];
            #pragma unroll
            for (int j = 0; j < 4; ++j) {
                int r = wr * 32 + mr * 16 + lg * 4 + j;
                float v = fmaxf(acc[mr][nr][j] * alpha + beta, 0.0f);
                hs[r * 264 + c] = (bf16_t)v;
            }
        }
    __syncthreads();

    // GEMM1: z = h @ W1 ; A from hs (LDS), B direct from L2-resident W1t
    f32x4 acc2[2][2] = {};
    #pragma unroll
    for (int kf = 0; kf < 8; ++kf) {          // K = 256
        bf16x8 a[2], b[2];
        #pragma unroll
        for (int mr = 0; mr < 2; ++mr)
            a[mr] = *(const bf16x8*)(hs + (wr * 32 + mr * 16 + l15) * 264 + kf * 32 + lg * 8);
        #pragma unroll
        for (int nr = 0; nr < 2; ++nr) {
            int c = wc * 32 + nr * 16 + l15;
            b[nr] = *(const bf16x8*)(W1t + c * H0 + kf * 32 + lg * 8);
        }
        #pragma unroll
        for (int mr = 0; mr < 2; ++mr)
            #pragma unroll
            for (int nr = 0; nr < 2; ++nr)
                acc2[mr][nr] = __builtin_amdgcn_mfma_f32_16x16x32_bf16(a[mr], b[nr], acc2[mr][nr], 0, 0, 0);
    }

    // epilogue B: BN1 + ReLU -> z (bf16) to ws
    #pragma unroll
    for (int mr = 0; mr < 2; ++mr)
        #pragma unroll
        for (int nr = 0; nr < 2; ++nr) {
            int c = wc * 32 + nr * 16 + l15;
            float alpha = al1[c], beta = be1[c];
            #pragma unroll
            for (int j = 0; j < 4; ++j) {
                int r = wr * 32 + mr * 16 + lg * 4 + j;
                float v = fmaxf(acc2[mr][nr][j] * alpha + beta, 0.0f);
                z_ws[(m0 + r) * H1 + c] = (bf16_t)v;
            }
        }
}

// =====================================================================
// Head: z -> p (pass-1 sigmoid, MFMA) -> per-disease heads with DAG gather.
// Block = 512 threads = 8 waves, 128 rows (wave wid owns rows wid*16..+15).
// =====================================================================
__global__ __launch_bounds__(512, 4) void head_kernel(
    const bf16_t* __restrict__ z_ws,
    const bf16_t* __restrict__ Wzt, const bf16_t* __restrict__ wiT,
    const float* __restrict__ b_init, const float* __restrict__ Wp,
    const float* __restrict__ bh, const float* __restrict__ Wo,
    const float* __restrict__ bo, const float* __restrict__ pred_w,
    const int* __restrict__ pred_idx, float* __restrict__ out)
{
    __shared__ __align__(16) char smem[64768];
    bf16_t* zs  = (bf16_t*)smem;                       // [128][136] = 34816 B
    bf16_t* wis = (bf16_t*)(smem + 34816);             // [16][136]  =  4352 B
    float*  ps  = (float*)(smem + 34816 + 4352);       // [128][16] f32 = 8192 B
    bf16_t* wzs = (bf16_t*)(smem + 34816 + 4352 + 8192); // [64][136] = 17408 B

    const int tid  = threadIdx.x;
    const int lane = tid & 63, wid = tid >> 6;
    const int l15 = lane & 15, lg = lane >> 4;
    const int m0 = blockIdx.x * 128;

    // stage z tile
    #pragma unroll
    for (int i = 0; i < 4; ++i) {
        int flat = i * 512 + tid;                      // 0..2047
        int row = flat >> 4, k8 = (flat & 15) << 3;
        *(bf16x8*)(zs + row * 136 + k8) = *(const bf16x8*)(z_ws + (m0 + row) * H1 + k8);
    }
    // stage w_initT [16][128]
    if (tid < 256) {
        int row = tid >> 4, k8 = (tid & 15) << 3;
        *(bf16x8*)(wis + row * 136 + k8) = *(const bf16x8*)(wiT + row * H1 + k8);
    }
    __syncthreads();

    // p = sigmoid(z @ w_init^T); wave wid does its 16 rows, N padded to 16
    {
        f32x4 pacc = {};
        #pragma unroll
        for (int kf = 0; kf < 4; ++kf) {
            bf16x8 a = *(const bf16x8*)(zs + (wid * 16 + l15) * 136 + kf * 32 + lg * 8);
            bf16x8 b = *(const bf16x8*)(wis + l15 * 136 + kf * 32 + lg * 8);
            pacc = __builtin_amdgcn_mfma_f32_16x16x32_bf16(a, b, pacc, 0, 0, 0);
        }
        int d = l15;
        float bi = (d < NDIS) ? b_init[d] : 0.0f;
        #pragma unroll
        for (int j = 0; j < 4; ++j) {
            int r = wid * 16 + lg * 4 + j;
            ps[r * 16 + d] = 1.0f / (1.0f + __expf(-(pacc[j] + bi)));
        }
    }
    __syncthreads();

    // per-disease heads
    for (int d = 0; d < NDIS; ++d) {
        // stage Wzt[d] : [64 h][128 e]
        #pragma unroll
        for (int i = 0; i < 2; ++i) {
            int flat = i * 512 + tid;                  // 0..1023
            int row = flat >> 4, k8 = (flat & 15) << 3;
            *(bf16x8*)(wzs + row * 136 + k8) = *(const bf16x8*)(Wzt + d * 8192 + row * H1 + k8);
        }
        __syncthreads();

        f32x4 acc[4] = {};
        #pragma unroll
        for (int kf = 0; kf < 4; ++kf) {
            bf16x8 a = *(const bf16x8*)(zs + (wid * 16 + l15) * 136 + kf * 32 + lg * 8);
            #pragma unroll
            for (int nr = 0; nr < 4; ++nr) {
                bf16x8 b = *(const bf16x8*)(wzs + (nr * 16 + l15) * 136 + kf * 32 + lg * 8);
                acc[nr] = __builtin_amdgcn_mfma_f32_16x16x32_bf16(a, b, acc[nr], 0, 0, 0);
            }
        }

        // epilogue: + aug@Wp + bh, ReLU, dot Wo (shfl reduce over 16 lanes), sigmoid
        int i0 = pred_idx[d * 3 + 0], i1 = pred_idx[d * 3 + 1], i2 = pred_idx[d * 3 + 2];
        float w0p = pred_w[d * 3 + 0], w1p = pred_w[d * 3 + 1], w2p = pred_w[d * 3 + 2];
        float bod = bo[d];

        float aug0[4], aug1[4], aug2[4];
        #pragma unroll
        for (int j = 0; j < 4; ++j) {
            int r = wid * 16 + lg * 4 + j;
            aug0[j] = ps[r * 16 + i0] * w0p;
            aug1[j] = ps[r * 16 + i1] * w1p;
            aug2[j] = ps[r * 16 + i2] * w2p;
        }
        float res[4] = {0.f, 0.f, 0.f, 0.f};
        #pragma unroll
        for (int nr = 0; nr < 4; ++nr) {
            int c = nr * 16 + l15;
            float bhv = bh[d * 64 + c];
            float wp0 = Wp[d * 192 + c], wp1 = Wp[d * 192 + 64 + c], wp2 = Wp[d * 192 + 128 + c];
            float wov = Wo[d * 64 + c];
            #pragma unroll
            for (int j = 0; j < 4; ++j) {
                float v = acc[nr][j] + bhv + aug0[j] * wp0 + aug1[j] * wp1 + aug2[j] * wp2;
                res[j] += fmaxf(v, 0.0f) * wov;
            }
        }
        #pragma unroll
        for (int j = 0; j < 4; ++j) {
            float s = res[j];
            s += __shfl_xor(s, 1); s += __shfl_xor(s, 2);
            s += __shfl_xor(s, 4); s += __shfl_xor(s, 8);
            if (l15 == 0) {
                int r = wid * 16 + lg * 4 + j;
                out[(m0 + r) * NDIS + d] = 1.0f / (1.0f + __expf(-(s + bod)));
            }
        }
        __syncthreads();
    }
}

// =====================================================================
extern "C" void kernel_launch(void* const* d_in, const int* in_sizes, int n_in,
                              void* d_out, int out_size, void* d_ws, size_t ws_size,
                              hipStream_t stream) {
    if (ws_size < (size_t)WS_NEED) return;  // need ~16.5 MiB scratch

    const float* x      = (const float*)d_in[0];
    const float* W0     = (const float*)d_in[1];
    const float* b0     = (const float*)d_in[2];
    const float* g0     = (const float*)d_in[3];
    const float* bb0    = (const float*)d_in[4];
    const float* mm0    = (const float*)d_in[5];
    const float* vv0    = (const float*)d_in[6];
    const float* W1     = (const float*)d_in[7];
    const float* b1     = (const float*)d_in[8];
    const float* g1     = (const float*)d_in[9];
    const float* bb1    = (const float*)d_in[10];
    const float* mm1    = (const float*)d_in[11];
    const float* vv1    = (const float*)d_in[12];
    const float* w_init = (const float*)d_in[13];
    const float* b_init = (const float*)d_in[14];
    const float* Wz     = (const float*)d_in[15];
    const float* Wp     = (const float*)d_in[16];
    const float* bh     = (const float*)d_in[17];
    const float* Wo     = (const float*)d_in[18];
    const float* bo     = (const float*)d_in[19];
    const float* pred_w = (const float*)d_in[20];
    const int*   pred_idx = (const int*)d_in[21];

    char* ws = (char*)d_ws;
    bf16_t* W0t = (bf16_t*)(ws + WS_W0T);
    bf16_t* W1t = (bf16_t*)(ws + WS_W1T);
    bf16_t* Wzt = (bf16_t*)(ws + WS_WZT);
    bf16_t* wiT = (bf16_t*)(ws + WS_WIT);
    float* al0 = (float*)(ws + WS_AL0);
    float* be0 = (float*)(ws + WS_BE0);
    float* al1 = (float*)(ws + WS_AL1);
    float* be1 = (float*)(ws + WS_BE1);
    bf16_t* z_ws = (bf16_t*)(ws + WS_Z);

    prep_kernel<<<dim3(512), dim3(256), 0, stream>>>(
        W0, b0, g0, bb0, mm0, vv0, W1, b1, g1, bb1, mm1, vv1, w_init, Wz, ws);

    enc_kernel<<<dim3(B_TOT / 64), dim3(512), 0, stream>>>(
        x, W0t, W1t, al0, be0, al1, be1, z_ws);

    head_kernel<<<dim3(B_TOT / 128), dim3(512), 0, stream>>>(
        z_ws, Wzt, wiT, b_init, Wp, bh, Wo, bo, pred_w, pred_idx, (float*)d_out);
}

// Round 2
// 91.328 us; speedup vs baseline: 1.0417x; 1.0417x over previous
//
#include <hip/hip_runtime.h>

// Problem constants
#define B_TOT   65536
#define IN_DIM  512
#define H0      256
#define H1      128
#define HH      64
#define NDIS    12

typedef __bf16 bf16_t;
typedef __bf16 bf16x4 __attribute__((ext_vector_type(4)));
typedef __bf16 bf16x8 __attribute__((ext_vector_type(8)));
typedef float  f32x4  __attribute__((ext_vector_type(4)));
typedef float  floatx4 __attribute__((ext_vector_type(4)));

// ---- workspace layout (bytes) ----
#define WS_W0T   0u          // bf16 [256][512]  (W0t[c][k] = W0[k][c])
#define WS_W1T   262144u     // bf16 [128][256]
#define WS_WZT   327680u     // bf16 [12][64][128] (Wzt[d][h][e] = Wz[d][e][h])
#define WS_WIT   524288u     // bf16 [16][128]  (w_init rows, zero-padded to 16)
#define WS_AL0   528384u     // f32 [256]
#define WS_BE0   529408u     // f32 [256]
#define WS_AL1   530432u     // f32 [128]
#define WS_BE1   530944u     // f32 [128]
#define WS_NEED  531456u

// ---- fused-kernel LDS layout (bytes) ----
// P0 (GEMM0 dbuf): buf0 @0 (xs 5120 + w0s 20480), buf1 @25600      [0..51200)
// P1: hs[64][264] bf16 @0                                           [0..33792)
// P2: zs[64][136] bf16 @34816                                       [34816..52224)
// P3: ps[64][16] f32 @52224 ; wis[16][136] bf16 @56320              [..60672)
// P4: wzs[2][64][136] bf16 @0                                       [0..34816)
#define L_XS0    0u
#define L_W0S0   5120u
#define L_XS1    25600u
#define L_W0S1   30720u
#define L_HS     0u
#define L_WZS    0u
#define L_ZS     34816u
#define L_PS     52224u
#define L_WIS    56320u
#define L_TOTAL  60672u

// =====================================================================
// Prep: transpose + f32->bf16 weights, fold BN (+linear bias) into alpha/beta
// =====================================================================
__global__ void prep_kernel(const float* __restrict__ W0, const float* __restrict__ b0,
                            const float* __restrict__ g0, const float* __restrict__ bb0,
                            const float* __restrict__ mm0, const float* __restrict__ vv0,
                            const float* __restrict__ W1, const float* __restrict__ b1,
                            const float* __restrict__ g1, const float* __restrict__ bb1,
                            const float* __restrict__ mm1, const float* __restrict__ vv1,
                            const float* __restrict__ w_init, const float* __restrict__ Wz,
                            char* __restrict__ ws)
{
    bf16_t* W0t = (bf16_t*)(ws + WS_W0T);
    bf16_t* W1t = (bf16_t*)(ws + WS_W1T);
    bf16_t* Wzt = (bf16_t*)(ws + WS_WZT);
    bf16_t* wiT = (bf16_t*)(ws + WS_WIT);
    float* al0 = (float*)(ws + WS_AL0);
    float* be0 = (float*)(ws + WS_BE0);
    float* al1 = (float*)(ws + WS_AL1);
    float* be1 = (float*)(ws + WS_BE1);

    int t = blockIdx.x * 256 + threadIdx.x;   // 512*256 = 131072 threads

    { // W0t: 256*512 (one elem per thread)
        int c = t >> 9, k = t & 511;
        W0t[t] = (bf16_t)W0[k * H0 + c];
    }
    if (t < H1 * H0) { // W1t
        int c = t >> 8, k = t & 255;
        W1t[t] = (bf16_t)W1[k * H1 + c];
    }
    if (t < NDIS * HH * H1) { // Wzt ; Wz is [12][128][64]
        int d = t >> 13, r = t & 8191, h = r >> 7, e = r & 127;
        Wzt[t] = (bf16_t)Wz[d * 8192 + e * 64 + h];
    }
    if (t < 16 * H1) { // w_initT (pad 12->16)
        int d = t >> 7, e = t & 127;
        wiT[t] = (d < NDIS) ? (bf16_t)w_init[d * H1 + e] : (bf16_t)0.0f;
    }
    if (t < H0) {
        float a = g0[t] * rsqrtf(vv0[t] + 1e-5f);
        al0[t] = a;
        be0[t] = (b0[t] - mm0[t]) * a + bb0[t];
    }
    if (t < H1) {
        float a = g1[t] * rsqrtf(vv1[t] + 1e-5f);
        al1[t] = a;
        be1[t] = (b1[t] - mm1[t]) * a + bb1[t];
    }
}

// =====================================================================
// Fused kernel: 64 rows per block, end-to-end (encoder + heads).
// 512 threads = 8 waves. GEMM0 waves arranged 2x4.
// =====================================================================
__global__ __launch_bounds__(512, 3) void fused_kernel(
    const float* __restrict__ x,
    const bf16_t* __restrict__ W0t, const bf16_t* __restrict__ W1t,
    const float* __restrict__ al0, const float* __restrict__ be0,
    const float* __restrict__ al1, const float* __restrict__ be1,
    const bf16_t* __restrict__ Wzt, const bf16_t* __restrict__ wiT,
    const float* __restrict__ b_init, const float* __restrict__ Wp,
    const float* __restrict__ bh, const float* __restrict__ Wo,
    const float* __restrict__ bo, const float* __restrict__ pred_w,
    const int* __restrict__ pred_idx, float* __restrict__ out)
{
    __shared__ __align__(16) char smem[L_TOTAL];

    const int tid  = threadIdx.x;
    const int lane = tid & 63, wid = tid >> 6;
    const int l15 = lane & 15, lg = lane >> 4;
    const int m0 = blockIdx.x * 64;

    // ---------------- stage wis once (region never aliased) ----------------
    {
        bf16_t* wis = (bf16_t*)(smem + L_WIS);
        if (tid < 256) {
            int row = tid >> 4, k8 = (tid & 15) << 3;
            *(bf16x8*)(wis + row * 136 + k8) = *(const bf16x8*)(wiT + row * H1 + k8);
        }
    }

    // ---------------- P0: GEMM0 (64x512x256), BK=32, LDS double-buffered ----
    const int wr = wid >> 2, wc = wid & 3;
    // staging address precompute
    const int xrow = tid >> 3, xc4 = (tid & 7) << 2;            // x: 64 rows x 32 cols f32
    const int wrow = tid >> 2, wk8 = (tid & 3) << 3;            // w0: rows tid>>2 and +128
    const float*  xp  = x + (m0 + xrow) * IN_DIM + xc4;
    const bf16_t* wp0 = W0t + wrow * IN_DIM + wk8;
    const bf16_t* wp1 = W0t + (wrow + 128) * IN_DIM + wk8;

    bf16_t* xsb[2]  = { (bf16_t*)(smem + L_XS0),  (bf16_t*)(smem + L_XS1)  };
    bf16_t* w0sb[2] = { (bf16_t*)(smem + L_W0S0), (bf16_t*)(smem + L_W0S1) };

    floatx4 xvA, xvB;
    bf16x8  wvA0, wvA1, wvB0, wvB1;

#define LOAD_A(ks) { xvA = *(const floatx4*)(xp + (ks) * 32); \
                     wvA0 = *(const bf16x8*)(wp0 + (ks) * 32); \
                     wvA1 = *(const bf16x8*)(wp1 + (ks) * 32); }
#define LOAD_B(ks) { xvB = *(const floatx4*)(xp + (ks) * 32); \
                     wvB0 = *(const bf16x8*)(wp0 + (ks) * 32); \
                     wvB1 = *(const bf16x8*)(wp1 + (ks) * 32); }
#define STORE_A(bi) { bf16x4 xo; xo[0]=(bf16_t)xvA[0]; xo[1]=(bf16_t)xvA[1]; \
                      xo[2]=(bf16_t)xvA[2]; xo[3]=(bf16_t)xvA[3]; \
                      *(bf16x4*)(xsb[bi] + xrow * 40 + xc4) = xo; \
                      *(bf16x8*)(w0sb[bi] + wrow * 40 + wk8) = wvA0; \
                      *(bf16x8*)(w0sb[bi] + (wrow + 128) * 40 + wk8) = wvA1; }
#define STORE_B(bi) { bf16x4 xo; xo[0]=(bf16_t)xvB[0]; xo[1]=(bf16_t)xvB[1]; \
                      xo[2]=(bf16_t)xvB[2]; xo[3]=(bf16_t)xvB[3]; \
                      *(bf16x4*)(xsb[bi] + xrow * 40 + xc4) = xo; \
                      *(bf16x8*)(w0sb[bi] + wrow * 40 + wk8) = wvB0; \
                      *(bf16x8*)(w0sb[bi] + (wrow + 128) * 40 + wk8) = wvB1; }

    f32x4 acc[2][4] = {};
#define MFMA_STEP(bi) { bf16x8 a[2], b[4]; \
    _Pragma("unroll") \
    for (int mr = 0; mr < 2; ++mr) \
        a[mr] = *(const bf16x8*)(xsb[bi] + (wr * 32 + mr * 16 + l15) * 40 + lg * 8); \
    _Pragma("unroll") \
    for (int nr = 0; nr < 4; ++nr) \
        b[nr] = *(const bf16x8*)(w0sb[bi] + (wc * 64 + nr * 16 + l15) * 40 + lg * 8); \
    _Pragma("unroll") \
    for (int mr = 0; mr < 2; ++mr) \
        _Pragma("unroll") \
        for (int nr = 0; nr < 4; ++nr) \
            acc[mr][nr] = __builtin_amdgcn_mfma_f32_16x16x32_bf16(a[mr], b[nr], acc[mr][nr], 0, 0, 0); }

    LOAD_A(0);
    STORE_A(0);
    LOAD_B(1);
    __syncthreads();

    // invariant entering pair tt: buf0 = tile 2tt, B-regs = tile 2tt+1
    #pragma unroll
    for (int tt = 0; tt < 8; ++tt) {
        if (tt < 7) LOAD_A(2 * tt + 2);
        MFMA_STEP(0);
        STORE_B(1);                    // tile 2tt+1 -> buf1
        __syncthreads();
        if (tt < 7) LOAD_B(2 * tt + 3);
        MFMA_STEP(1);
        if (tt < 7) STORE_A(0);        // tile 2tt+2 -> buf0
        __syncthreads();
    }

    // ---------------- P1: BN0 + ReLU -> hs ----------------
    {
        bf16_t* hs = (bf16_t*)(smem + L_HS);
        #pragma unroll
        for (int mr = 0; mr < 2; ++mr)
            #pragma unroll
            for (int nr = 0; nr < 4; ++nr) {
                int c = wc * 64 + nr * 16 + l15;
                float alpha = al0[c], beta = be0[c];
                #pragma unroll
                for (int j = 0; j < 4; ++j) {
                    int r = wr * 32 + mr * 16 + lg * 4 + j;
                    float v = fmaxf(acc[mr][nr][j] * alpha + beta, 0.0f);
                    hs[r * 264 + c] = (bf16_t)v;
                }
            }
    }
    __syncthreads();

    // ---------------- P2: GEMM1 (64x256x128), A from hs, B direct L2 -------
    {
        bf16_t* hs = (bf16_t*)(smem + L_HS);
        bf16_t* zs = (bf16_t*)(smem + L_ZS);
        f32x4 acc2[2][2] = {};
        #pragma unroll
        for (int kf = 0; kf < 8; ++kf) {
            bf16x8 a[2], b[2];
            #pragma unroll
            for (int mr = 0; mr < 2; ++mr)
                a[mr] = *(const bf16x8*)(hs + (wr * 32 + mr * 16 + l15) * 264 + kf * 32 + lg * 8);
            #pragma unroll
            for (int nr = 0; nr < 2; ++nr) {
                int c = wc * 32 + nr * 16 + l15;
                b[nr] = *(const bf16x8*)(W1t + c * H0 + kf * 32 + lg * 8);
            }
            #pragma unroll
            for (int mr = 0; mr < 2; ++mr)
                #pragma unroll
                for (int nr = 0; nr < 2; ++nr)
                    acc2[mr][nr] = __builtin_amdgcn_mfma_f32_16x16x32_bf16(a[mr], b[nr], acc2[mr][nr], 0, 0, 0);
        }
        // BN1 + ReLU -> zs (bf16) ; zs region disjoint from hs
        #pragma unroll
        for (int mr = 0; mr < 2; ++mr)
            #pragma unroll
            for (int nr = 0; nr < 2; ++nr) {
                int c = wc * 32 + nr * 16 + l15;
                float alpha = al1[c], beta = be1[c];
                #pragma unroll
                for (int j = 0; j < 4; ++j) {
                    int r = wr * 32 + mr * 16 + lg * 4 + j;
                    float v = fmaxf(acc2[mr][nr][j] * alpha + beta, 0.0f);
                    zs[r * 136 + c] = (bf16_t)v;
                }
            }
    }
    __syncthreads();

    // ---------------- P3: p = sigmoid(z @ w_init^T) ----------------
    {
        bf16_t* zs  = (bf16_t*)(smem + L_ZS);
        bf16_t* wis = (bf16_t*)(smem + L_WIS);
        float*  ps  = (float*)(smem + L_PS);
        if (wid < 4) {
            f32x4 pacc = {};
            #pragma unroll
            for (int kf = 0; kf < 4; ++kf) {
                bf16x8 a = *(const bf16x8*)(zs + (wid * 16 + l15) * 136 + kf * 32 + lg * 8);
                bf16x8 b = *(const bf16x8*)(wis + l15 * 136 + kf * 32 + lg * 8);
                pacc = __builtin_amdgcn_mfma_f32_16x16x32_bf16(a, b, pacc, 0, 0, 0);
            }
            int d = l15;
            float bi = (d < NDIS) ? b_init[d] : 0.0f;
            #pragma unroll
            for (int j = 0; j < 4; ++j) {
                int r = wid * 16 + lg * 4 + j;
                ps[r * 16 + d] = 1.0f / (1.0f + __expf(-(pacc[j] + bi)));
            }
        }
    }
    __syncthreads();

    // ---------------- P4: 12 heads, 2 d-groups x 6 iterations ----------------
    {
        bf16_t* zs  = (bf16_t*)(smem + L_ZS);
        float*  ps  = (float*)(smem + L_PS);
        const int g  = wid >> 2;          // d-group: waves 0-3 -> d 0..5, waves 4-7 -> d 6..11
        const int mt = wid & 3;           // M-tile (16 rows)
        const int lt = tid & 255;         // tid within group
        bf16_t* wzs = (bf16_t*)(smem + L_WZS) + g * 8704;   // [64][136] per group

        for (int i = 0; i < 6; ++i) {
            int d = g * 6 + i;
            // stage Wzt[d] (16KB) by this group's 256 threads
            #pragma unroll
            for (int j = 0; j < 4; ++j) {
                int chunk = j * 256 + lt;
                int row = chunk >> 4, k8 = (chunk & 15) << 3;
                *(bf16x8*)(wzs + row * 136 + k8) = *(const bf16x8*)(Wzt + d * 8192 + row * H1 + k8);
            }
            __syncthreads();

            f32x4 hacc[4] = {};
            #pragma unroll
            for (int kf = 0; kf < 4; ++kf) {
                bf16x8 a = *(const bf16x8*)(zs + (mt * 16 + l15) * 136 + kf * 32 + lg * 8);
                #pragma unroll
                for (int nr = 0; nr < 4; ++nr) {
                    bf16x8 b = *(const bf16x8*)(wzs + (nr * 16 + l15) * 136 + kf * 32 + lg * 8);
                    hacc[nr] = __builtin_amdgcn_mfma_f32_16x16x32_bf16(a, b, hacc[nr], 0, 0, 0);
                }
            }

            // epilogue: + aug@Wp + bh, ReLU, dot Wo, sigmoid
            int i0 = pred_idx[d * 3 + 0], i1 = pred_idx[d * 3 + 1], i2 = pred_idx[d * 3 + 2];
            float w0p = pred_w[d * 3 + 0], w1p = pred_w[d * 3 + 1], w2p = pred_w[d * 3 + 2];
            float bod = bo[d];

            float aug0[4], aug1[4], aug2[4];
            #pragma unroll
            for (int j = 0; j < 4; ++j) {
                int r = mt * 16 + lg * 4 + j;
                aug0[j] = ps[r * 16 + i0] * w0p;
                aug1[j] = ps[r * 16 + i1] * w1p;
                aug2[j] = ps[r * 16 + i2] * w2p;
            }
            float res[4] = {0.f, 0.f, 0.f, 0.f};
            #pragma unroll
            for (int nr = 0; nr < 4; ++nr) {
                int c = nr * 16 + l15;
                float bhv = bh[d * 64 + c];
                float wpa = Wp[d * 192 + c], wpb = Wp[d * 192 + 64 + c], wpc = Wp[d * 192 + 128 + c];
                float wov = Wo[d * 64 + c];
                #pragma unroll
                for (int j = 0; j < 4; ++j) {
                    float v = hacc[nr][j] + bhv + aug0[j] * wpa + aug1[j] * wpb + aug2[j] * wpc;
                    res[j] += fmaxf(v, 0.0f) * wov;
                }
            }
            #pragma unroll
            for (int j = 0; j < 4; ++j) {
                float s = res[j];
                s += __shfl_xor(s, 1); s += __shfl_xor(s, 2);
                s += __shfl_xor(s, 4); s += __shfl_xor(s, 8);
                if (l15 == 0) {
                    int r = mt * 16 + lg * 4 + j;
                    out[(m0 + r) * NDIS + d] = 1.0f / (1.0f + __expf(-(s + bod)));
                }
            }
            __syncthreads();
        }
    }
}

// =====================================================================
extern "C" void kernel_launch(void* const* d_in, const int* in_sizes, int n_in,
                              void* d_out, int out_size, void* d_ws, size_t ws_size,
                              hipStream_t stream) {
    if (ws_size < (size_t)WS_NEED) return;

    const float* x      = (const float*)d_in[0];
    const float* W0     = (const float*)d_in[1];
    const float* b0     = (const float*)d_in[2];
    const float* g0     = (const float*)d_in[3];
    const float* bb0    = (const float*)d_in[4];
    const float* mm0    = (const float*)d_in[5];
    const float* vv0    = (const float*)d_in[6];
    const float* W1     = (const float*)d_in[7];
    const float* b1     = (const float*)d_in[8];
    const float* g1     = (const float*)d_in[9];
    const float* bb1    = (const float*)d_in[10];
    const float* vv1_   = (const float*)d_in[12];
    const float* mm1    = (const float*)d_in[11];
    const float* w_init = (const float*)d_in[13];
    const float* b_init = (const float*)d_in[14];
    const float* Wz     = (const float*)d_in[15];
    const float* Wp     = (const float*)d_in[16];
    const float* bh     = (const float*)d_in[17];
    const float* Wo     = (const float*)d_in[18];
    const float* bo     = (const float*)d_in[19];
    const float* pred_w = (const float*)d_in[20];
    const int*   pred_idx = (const int*)d_in[21];

    char* ws = (char*)d_ws;
    const bf16_t* W0t = (const bf16_t*)(ws + WS_W0T);
    const bf16_t* W1t = (const bf16_t*)(ws + WS_W1T);
    const bf16_t* Wzt = (const bf16_t*)(ws + WS_WZT);
    const bf16_t* wiT = (const bf16_t*)(ws + WS_WIT);
    const float* al0 = (const float*)(ws + WS_AL0);
    const float* be0 = (const float*)(ws + WS_BE0);
    const float* al1 = (const float*)(ws + WS_AL1);
    const float* be1 = (const float*)(ws + WS_BE1);

    prep_kernel<<<dim3(512), dim3(256), 0, stream>>>(
        W0, b0, g0, bb0, mm0, vv0, W1, b1, g1, bb1, mm1, vv1_, w_init, Wz, ws);

    fused_kernel<<<dim3(B_TOT / 64), dim3(512), 0, stream>>>(
        x, W0t, W1t, al0, be0, al1, be1, Wzt, wiT, b_init, Wp, bh, Wo, bo,
        pred_w, pred_idx, (float*)d_out);
}